// Round 4
// baseline (704.685 us; speedup 1.0000x reference)
//
#include <hip/hip_runtime.h>
#include <stdint.h>

// Problem constants (fixed by setup_inputs shapes)
#define B_   32
#define C_   192
#define Hh   64
#define Ww   64
#define LS   256    // 16*16 pooled positions
#define DI   384    // d_inner
#define DSt  16     // d_state
#define E2   768    // 2*d_inner

// ---------------------------------------------------------------------------
// K1: 4x4 avg-pool + LayerNorm over C=192. One block per (b, pooled pos).
// ---------------------------------------------------------------------------
__global__ __launch_bounds__(192) void k_pool_ln(
    const float* __restrict__ x, const float* __restrict__ w, const float* __restrict__ bb,
    float* __restrict__ xln)
{
  int row = blockIdx.x;            // b*256 + ls
  int b = row >> 8, ls = row & 255;
  int i = ls >> 4, j = ls & 15;
  int c = threadIdx.x;
  const float* xp = x + (((size_t)(b * C_ + c) * Hh + i * 4) * Ww + j * 4);
  float s = 0.f;
#pragma unroll
  for (int r = 0; r < 4; ++r) {
    float4 v = *reinterpret_cast<const float4*>(xp + (size_t)r * Ww);
    s += v.x + v.y + v.z + v.w;
  }
  float pooled = s * (1.f / 16.f);
  float s1 = pooled, s2 = pooled * pooled;
#pragma unroll
  for (int off = 32; off; off >>= 1) {
    s1 += __shfl_xor(s1, off, 64);
    s2 += __shfl_xor(s2, off, 64);
  }
  __shared__ float a1[3], a2[3], mv[2];
  int wid = c >> 6;
  if ((c & 63) == 0) { a1[wid] = s1; a2[wid] = s2; }
  __syncthreads();
  if (c == 0) {
    float t1 = a1[0] + a1[1] + a1[2], t2 = a2[0] + a2[1] + a2[2];
    float mu = t1 / 192.f;
    float var = t2 / 192.f - mu * mu;
    mv[0] = mu; mv[1] = rsqrtf(var + 1e-5f);
  }
  __syncthreads();
  float val = (pooled - mv[0]) * mv[1] * w[c] + bb[c];
  xln[(size_t)row * C_ + c] = val;
}

// ---------------------------------------------------------------------------
// K2/K7: f32 NT GEMM. C[m,n] = sum_k A[m,k]*W[n,k].
// 128x128 block tile, BK=8, 256 threads, 8x8 register tile per thread.
// LDS transposed (At[k][m]) so inner reads are ds_read_b128.
// M % 128 == 0, K % 8 == 0; N guarded (clamped W loads + store guard).
// ---------------------------------------------------------------------------
__global__ __launch_bounds__(256) void k_gemm_f32(
    const float* __restrict__ A, const float* __restrict__ W,
    float* __restrict__ C, int N, int K)
{
  __shared__ float At[8][132];
  __shared__ float Wt[8][132];
  int tid = threadIdx.x;
  int m0 = blockIdx.y * 128, n0 = blockIdx.x * 128;
  int tx = tid & 15, ty = tid >> 4;
  int lr = tid >> 1, lk = (tid & 1) * 4;
  float acc[8][8] = {};
  const float* Arow = A + (size_t)(m0 + lr) * K + lk;
  int wrow = n0 + lr; if (wrow >= N) wrow = N - 1;
  const float* Wrow = W + (size_t)wrow * K + lk;
  for (int k0 = 0; k0 < K; k0 += 8) {
    float4 av = *reinterpret_cast<const float4*>(Arow + k0);
    float4 wv = *reinterpret_cast<const float4*>(Wrow + k0);
    __syncthreads();
    At[lk + 0][lr] = av.x; At[lk + 1][lr] = av.y; At[lk + 2][lr] = av.z; At[lk + 3][lr] = av.w;
    Wt[lk + 0][lr] = wv.x; Wt[lk + 1][lr] = wv.y; Wt[lk + 2][lr] = wv.z; Wt[lk + 3][lr] = wv.w;
    __syncthreads();
#pragma unroll
    for (int k = 0; k < 8; ++k) {
      float4 a0 = *reinterpret_cast<const float4*>(&At[k][8 * ty]);
      float4 a1 = *reinterpret_cast<const float4*>(&At[k][8 * ty + 4]);
      float4 w0 = *reinterpret_cast<const float4*>(&Wt[k][8 * tx]);
      float4 w1 = *reinterpret_cast<const float4*>(&Wt[k][8 * tx + 4]);
      float a[8] = {a0.x, a0.y, a0.z, a0.w, a1.x, a1.y, a1.z, a1.w};
      float w[8] = {w0.x, w0.y, w0.z, w0.w, w1.x, w1.y, w1.z, w1.w};
#pragma unroll
      for (int i = 0; i < 8; ++i)
#pragma unroll
        for (int j = 0; j < 8; ++j) acc[i][j] += a[i] * w[j];
    }
  }
#pragma unroll
  for (int i = 0; i < 8; ++i) {
    int row = m0 + 8 * ty + i;
    int col0 = n0 + 8 * tx;
    if (col0 < N)
      *reinterpret_cast<float4*>(C + (size_t)row * N + col0) =
          make_float4(acc[i][0], acc[i][1], acc[i][2], acc[i][3]);
    if (col0 + 4 < N)
      *reinterpret_cast<float4*>(C + (size_t)row * N + col0 + 4) =
          make_float4(acc[i][4], acc[i][5], acc[i][6], acc[i][7]);
  }
}

// ---------------------------------------------------------------------------
// K3: depthwise conv1d (k=3, zero pad) over seq + SiLU. One thread per (b,l,e).
// ---------------------------------------------------------------------------
__global__ __launch_bounds__(256) void k_conv_silu(
    const float* __restrict__ xz, const float* __restrict__ cw, const float* __restrict__ cb,
    float* __restrict__ xc)
{
  int idx = blockIdx.x * 256 + threadIdx.x;   // (b*256+l)*384 + e
  int e = idx % DI;
  int row = idx / DI;
  int l = row & 255;
  const float* xin = xz + (size_t)row * E2 + e;
  float x0 = *xin;
  float xm = (l > 0)   ? *(xin - E2) : 0.f;
  float xp = (l < 255) ? *(xin + E2) : 0.f;
  float v = cw[e * 3 + 0] * xm + cw[e * 3 + 1] * x0 + cw[e * 3 + 2] * xp + cb[e];
  xc[idx] = v / (1.f + expf(-v));
}

// ---------------------------------------------------------------------------
// K4: x_proj (33 dots of len 384) + dt_proj + softplus. One wave per (b,l) row.
// ---------------------------------------------------------------------------
__global__ __launch_bounds__(256) void k_xproj(
    const float* __restrict__ xc, const float* __restrict__ xw,
    const float* __restrict__ dtw, const float* __restrict__ dtb,
    float* __restrict__ BC, float* __restrict__ delta)
{
  int wid = threadIdx.x >> 6, lane = threadIdx.x & 63;
  int row = blockIdx.x * 4 + wid;
  const float* xr = xc + (size_t)row * DI;
  float xv[6];
#pragma unroll
  for (int k = 0; k < 6; ++k) xv[k] = xr[lane + 64 * k];
  float dres = 0.f, mine = 0.f;
  for (int j = 0; j < 33; ++j) {
    const float* wr = xw + (size_t)j * DI;
    float p = 0.f;
#pragma unroll
    for (int k = 0; k < 6; ++k) p += wr[lane + 64 * k] * xv[k];
#pragma unroll
    for (int off = 32; off; off >>= 1) p += __shfl_xor(p, off, 64);
    if (j == 0) dres = p;
    else if (lane == j - 1) mine = p;
  }
  if (lane < 32) BC[(size_t)row * 32 + lane] = mine;   // [0..15]=B_mat, [16..31]=C_mat
#pragma unroll
  for (int k = 0; k < 6; ++k) {
    int e = lane + 64 * k;
    float dr = dres * dtw[e] + dtb[e];
    delta[(size_t)row * DI + e] = dr > 20.f ? dr : log1pf(expf(dr));
  }
}

// ---------------------------------------------------------------------------
// K5: selective scan. Thread per (b,e,s); 16-lane shfl reduce over s.
// Fuses + xc*D and * silu(z) into the y write.
// ---------------------------------------------------------------------------
__global__ __launch_bounds__(256) void k_scan(
    const float* __restrict__ delta, const float* __restrict__ xc,
    const float* __restrict__ BC, const float* __restrict__ xz,
    const float* __restrict__ A_log, const float* __restrict__ Dp,
    float* __restrict__ yg)
{
  int blk = blockIdx.x;
  int b = blk / 24, eg16 = blk % 24;
  int s = threadIdx.x & 15, eg = threadIdx.x >> 4;
  int e = eg16 * 16 + eg;
  float Aes = -expf(A_log[e * DSt + s]);
  float Dv = Dp[e];
  size_t rbase = (size_t)b * 256;
  const float* pd = delta + rbase * DI + e;
  const float* px = xc + rbase * DI + e;
  const float* pb = BC + rbase * 32 + s;
  const float* pz = xz + rbase * E2 + DI + e;
  float* py = yg + rbase * DI + e;
  float h = 0.f;
  for (int l = 0; l < 256; ++l) {
    float dv  = pd[(size_t)l * DI];
    float xcv = px[(size_t)l * DI];
    float Bm  = pb[(size_t)l * 32];
    float Cm  = pb[(size_t)l * 32 + 16];
    float da = expf(dv * Aes);
    h = da * h + dv * Bm * xcv;
    float contrib = h * Cm;
    contrib += __shfl_xor(contrib, 1, 64);
    contrib += __shfl_xor(contrib, 2, 64);
    contrib += __shfl_xor(contrib, 4, 64);
    contrib += __shfl_xor(contrib, 8, 64);
    if (s == 0) {
      float z = pz[(size_t)l * E2];
      float y = (contrib + xcv * Dv) * (z / (1.f + expf(-z)));
      py[(size_t)l * DI] = y;
    }
  }
}

// ---------------------------------------------------------------------------
// K6: LayerNorm over d_inner=384, f32 out.
// ---------------------------------------------------------------------------
__global__ __launch_bounds__(128) void k_ln_ssm(
    const float* __restrict__ yg, const float* __restrict__ nw, const float* __restrict__ nb,
    float* __restrict__ yn)
{
  int row = blockIdx.x;
  int t = threadIdx.x;
  const float* yr = yg + (size_t)row * DI;
  float v0 = yr[t], v1 = yr[t + 128], v2 = yr[t + 256];
  float s1 = v0 + v1 + v2, s2 = v0 * v0 + v1 * v1 + v2 * v2;
#pragma unroll
  for (int off = 32; off; off >>= 1) {
    s1 += __shfl_xor(s1, off, 64);
    s2 += __shfl_xor(s2, off, 64);
  }
  __shared__ float a1[2], a2[2];
  if ((t & 63) == 0) { a1[t >> 6] = s1; a2[t >> 6] = s2; }
  __syncthreads();
  float t1 = a1[0] + a1[1], t2 = a2[0] + a2[1];
  float mu = t1 / 384.f, var = t2 / 384.f - mu * mu;
  float rstd = rsqrtf(var + 1e-5f);
  float* yo = yn + (size_t)row * DI;
  yo[t]       = (v0 - mu) * rstd * nw[t]       + nb[t];
  yo[t + 128] = (v1 - mu) * rstd * nw[t + 128] + nb[t + 128];
  yo[t + 256] = (v2 - mu) * rstd * nw[t + 256] + nb[t + 256];
}

// ---------------------------------------------------------------------------
// K8: fused 7x7 depthwise conv + bilinear 4x upsample of ssm + gated combine.
// Block: one (b, c, 16-row strip). LDS: 22x72 f32 x-patch, 49 weights,
// 6x16 ssm rows. Thread computes 2x2 outputs (row-reuse on LDS reads).
// ---------------------------------------------------------------------------
__global__ __launch_bounds__(256) void k_final(
    const float* __restrict__ x, const float* __restrict__ dww, const float* __restrict__ dwb,
    const float* __restrict__ ssm, const float* __restrict__ gate,
    float* __restrict__ out)
{
  int blk = blockIdx.x;
  int ti = blk & 3;
  int c = (blk >> 2) % C_;
  int b = blk / (4 * C_);
  int h0 = ti * 16;
  __shared__ float xpatch[22 * 72];
  __shared__ float wlds[49];
  __shared__ float slds[6 * 16];
  __shared__ float biass;
  int tid = threadIdx.x;
  if (tid < 49) wlds[tid] = dww[(size_t)c * 49 + tid];
  if (tid == 49) biass = dwb[c];
  int ibase = (h0 >> 2) - 1;   // floor(h0*0.25 - 0.375)
  if (tid < 96) {
    int ii = ibase + (tid >> 4);
    ii = ii < 0 ? 0 : (ii > 15 ? 15 : ii);
    int jj = tid & 15;
    slds[tid] = ssm[((size_t)(b * LS) + ii * 16 + jj) * C_ + c];
  }
  const float* xb = x + ((size_t)(b * C_ + c) * Hh) * Ww;
  for (int idx = tid; idx < 22 * 70; idx += 256) {
    int r = idx / 70, col = idx % 70;
    int gh = h0 - 3 + r, gw = col - 3;
    float v = 0.f;
    if (gh >= 0 && gh < 64 && gw >= 0 && gw < 64)
      v = xb[gh * 64 + gw];
    xpatch[r * 72 + col] = v;
  }
  __syncthreads();
  float g = 1.f / (1.f + expf(-gate[0]));
  int qn = tid >> 5;             // 0..7
  int R0 = qn * 2;
  int w0 = (tid & 31) * 2;
  float a00 = 0, a01 = 0, a10 = 0, a11 = 0;
#pragma unroll
  for (int k = 0; k < 8; ++k) {
    const float* prow = &xpatch[(R0 + k) * 72 + w0];
    float v[8];
#pragma unroll
    for (int d = 0; d < 8; ++d) v[d] = prow[d];
    if (k < 7) {
#pragma unroll
      for (int dx = 0; dx < 7; ++dx) {
        float wv = wlds[k * 7 + dx];
        a00 += wv * v[dx]; a01 += wv * v[dx + 1];
      }
    }
    if (k > 0) {
#pragma unroll
      for (int dx = 0; dx < 7; ++dx) {
        float wv = wlds[(k - 1) * 7 + dx];
        a10 += wv * v[dx]; a11 += wv * v[dx + 1];
      }
    }
  }
  float locs[2][2] = {{a00 + biass, a01 + biass}, {a10 + biass, a11 + biass}};
  float* orow = out + ((size_t)(b * C_ + c) * Hh) * Ww;
#pragma unroll
  for (int rr = 0; rr < 2; ++rr) {
    int hgl = h0 + R0 + rr;
    float ci = hgl * 0.25f - 0.375f;
    float fif = floorf(ci);
    int i0 = (int)fif;
    float fi = ci - fif;
    int li = i0 - ibase;
    const float* r0p = &slds[li * 16];
    const float* r1p = &slds[(li + 1) * 16];
    float ov[2];
#pragma unroll
    for (int ccx = 0; ccx < 2; ++ccx) {
      int wgl = w0 + ccx;
      float cj = wgl * 0.25f - 0.375f;
      float fjf = floorf(cj);
      int j0 = (int)fjf;
      float fj = cj - fjf;
      int jc0 = j0 < 0 ? 0 : j0;
      int jc1 = (j0 + 1) > 15 ? 15 : (j0 + 1);
      float sv = (1.f - fi) * ((1.f - fj) * r0p[jc0] + fj * r0p[jc1])
               +         fi * ((1.f - fj) * r1p[jc0] + fj * r1p[jc1]);
      float xv = xpatch[(R0 + rr + 3) * 72 + (wgl + 3)];
      ov[ccx] = xv + g * sv + (1.f - g) * locs[rr][ccx];
    }
    *reinterpret_cast<float2*>(&orow[hgl * 64 + w0]) = make_float2(ov[0], ov[1]);
  }
}

// ---------------------------------------------------------------------------
extern "C" void kernel_launch(void* const* d_in, const int* in_sizes, int n_in,
                              void* d_out, int out_size, void* d_ws, size_t ws_size,
                              hipStream_t stream)
{
  const float* x    = (const float*)d_in[0];
  const float* inw  = (const float*)d_in[1];
  const float* xw   = (const float*)d_in[2];
  const float* dtw  = (const float*)d_in[3];
  const float* dtb  = (const float*)d_in[4];
  const float* cw   = (const float*)d_in[5];
  const float* cb   = (const float*)d_in[6];
  const float* alog = (const float*)d_in[7];
  const float* Dp   = (const float*)d_in[8];
  const float* ow   = (const float*)d_in[9];
  const float* nsw  = (const float*)d_in[10];
  const float* nsb  = (const float*)d_in[11];
  const float* n1w  = (const float*)d_in[12];
  const float* n1b  = (const float*)d_in[13];
  const float* dww  = (const float*)d_in[14];
  const float* dwb  = (const float*)d_in[15];
  const float* gate = (const float*)d_in[16];

  char* ws = (char*)d_ws;
  float* xln   = (float*)ws; ws += (size_t)8192 * 192 * 4;   // 6.3 MB
  float* xz    = (float*)ws; ws += (size_t)8192 * 768 * 4;   // 25.2 MB
  float* xc    = (float*)ws; ws += (size_t)8192 * 384 * 4;   // 12.6 MB
  float* delta = (float*)ws; ws += (size_t)8192 * 384 * 4;   // 12.6 MB
  float* BC    = (float*)ws; ws += (size_t)8192 * 32 * 4;    // 1.05 MB
  float* yg    = (float*)ws; ws += (size_t)8192 * 384 * 4;   // 12.6 MB
  float* yn  = xz;    // alias: xz dead after k_scan
  float* ssm = xln;   // alias: xln dead after gemm1

  k_pool_ln<<<8192, 192, 0, stream>>>(x, n1w, n1b, xln);
  k_gemm_f32<<<dim3(6, 64), 256, 0, stream>>>(xln, inw, xz, 768, 192);
  k_conv_silu<<<12288, 256, 0, stream>>>(xz, cw, cb, xc);
  k_xproj<<<2048, 256, 0, stream>>>(xc, xw, dtw, dtb, BC, delta);
  k_scan<<<768, 256, 0, stream>>>(delta, xc, BC, xz, alog, Dp, yg);
  k_ln_ssm<<<8192, 128, 0, stream>>>(yg, nsw, nsb, yn);
  k_gemm_f32<<<dim3(2, 64), 256, 0, stream>>>(yn, ow, ssm, 192, 384);
  k_final<<<24576, 256, 0, stream>>>(x, dww, dwb, ssm, gate, (float*)d_out);
}

// Round 5
// 613.516 us; speedup vs baseline: 1.1486x; 1.1486x over previous
//
#include <hip/hip_runtime.h>
#include <stdint.h>

// Problem constants (fixed by setup_inputs shapes)
#define B_   32
#define C_   192
#define Hh   64
#define Ww   64
#define LS   256    // 16*16 pooled positions
#define DI   384    // d_inner
#define DSt  16     // d_state
#define E2   768    // 2*d_inner

// ---------------------------------------------------------------------------
// K1: 4x4 avg-pool + LayerNorm over C=192. One block per (b, pooled pos).
// ---------------------------------------------------------------------------
__global__ __launch_bounds__(192) void k_pool_ln(
    const float* __restrict__ x, const float* __restrict__ w, const float* __restrict__ bb,
    float* __restrict__ xln)
{
  int row = blockIdx.x;            // b*256 + ls
  int b = row >> 8, ls = row & 255;
  int i = ls >> 4, j = ls & 15;
  int c = threadIdx.x;
  const float* xp = x + (((size_t)(b * C_ + c) * Hh + i * 4) * Ww + j * 4);
  float s = 0.f;
#pragma unroll
  for (int r = 0; r < 4; ++r) {
    float4 v = *reinterpret_cast<const float4*>(xp + (size_t)r * Ww);
    s += v.x + v.y + v.z + v.w;
  }
  float pooled = s * (1.f / 16.f);
  float s1 = pooled, s2 = pooled * pooled;
#pragma unroll
  for (int off = 32; off; off >>= 1) {
    s1 += __shfl_xor(s1, off, 64);
    s2 += __shfl_xor(s2, off, 64);
  }
  __shared__ float a1[3], a2[3], mv[2];
  int wid = c >> 6;
  if ((c & 63) == 0) { a1[wid] = s1; a2[wid] = s2; }
  __syncthreads();
  if (c == 0) {
    float t1 = a1[0] + a1[1] + a1[2], t2 = a2[0] + a2[1] + a2[2];
    float mu = t1 / 192.f;
    float var = t2 / 192.f - mu * mu;
    mv[0] = mu; mv[1] = rsqrtf(var + 1e-5f);
  }
  __syncthreads();
  float val = (pooled - mv[0]) * mv[1] * w[c] + bb[c];
  xln[(size_t)row * C_ + c] = val;
}

// ---------------------------------------------------------------------------
// K2/K7: f32 NT GEMM. C[m,n] = sum_k A[m,k]*W[n,k].
// 128x128 block tile, BK=8, 256 threads, 8x8 register tile per thread.
// ---------------------------------------------------------------------------
__global__ __launch_bounds__(256) void k_gemm_f32(
    const float* __restrict__ A, const float* __restrict__ W,
    float* __restrict__ C, int N, int K)
{
  __shared__ float At[8][132];
  __shared__ float Wt[8][132];
  int tid = threadIdx.x;
  int m0 = blockIdx.y * 128, n0 = blockIdx.x * 128;
  int tx = tid & 15, ty = tid >> 4;
  int lr = tid >> 1, lk = (tid & 1) * 4;
  float acc[8][8] = {};
  const float* Arow = A + (size_t)(m0 + lr) * K + lk;
  int wrow = n0 + lr; if (wrow >= N) wrow = N - 1;
  const float* Wrow = W + (size_t)wrow * K + lk;
  for (int k0 = 0; k0 < K; k0 += 8) {
    float4 av = *reinterpret_cast<const float4*>(Arow + k0);
    float4 wv = *reinterpret_cast<const float4*>(Wrow + k0);
    __syncthreads();
    At[lk + 0][lr] = av.x; At[lk + 1][lr] = av.y; At[lk + 2][lr] = av.z; At[lk + 3][lr] = av.w;
    Wt[lk + 0][lr] = wv.x; Wt[lk + 1][lr] = wv.y; Wt[lk + 2][lr] = wv.z; Wt[lk + 3][lr] = wv.w;
    __syncthreads();
#pragma unroll
    for (int k = 0; k < 8; ++k) {
      float4 a0 = *reinterpret_cast<const float4*>(&At[k][8 * ty]);
      float4 a1 = *reinterpret_cast<const float4*>(&At[k][8 * ty + 4]);
      float4 w0 = *reinterpret_cast<const float4*>(&Wt[k][8 * tx]);
      float4 w1 = *reinterpret_cast<const float4*>(&Wt[k][8 * tx + 4]);
      float a[8] = {a0.x, a0.y, a0.z, a0.w, a1.x, a1.y, a1.z, a1.w};
      float w[8] = {w0.x, w0.y, w0.z, w0.w, w1.x, w1.y, w1.z, w1.w};
#pragma unroll
      for (int i = 0; i < 8; ++i)
#pragma unroll
        for (int j = 0; j < 8; ++j) acc[i][j] += a[i] * w[j];
    }
  }
#pragma unroll
  for (int i = 0; i < 8; ++i) {
    int row = m0 + 8 * ty + i;
    int col0 = n0 + 8 * tx;
    if (col0 < N)
      *reinterpret_cast<float4*>(C + (size_t)row * N + col0) =
          make_float4(acc[i][0], acc[i][1], acc[i][2], acc[i][3]);
    if (col0 + 4 < N)
      *reinterpret_cast<float4*>(C + (size_t)row * N + col0 + 4) =
          make_float4(acc[i][4], acc[i][5], acc[i][6], acc[i][7]);
  }
}

// ---------------------------------------------------------------------------
// K3: depthwise conv1d (k=3, zero pad) over seq + SiLU. One thread per (b,l,e).
// ---------------------------------------------------------------------------
__global__ __launch_bounds__(256) void k_conv_silu(
    const float* __restrict__ xz, const float* __restrict__ cw, const float* __restrict__ cb,
    float* __restrict__ xc)
{
  int idx = blockIdx.x * 256 + threadIdx.x;   // (b*256+l)*384 + e
  int e = idx % DI;
  int row = idx / DI;
  int l = row & 255;
  const float* xin = xz + (size_t)row * E2 + e;
  float x0 = *xin;
  float xm = (l > 0)   ? *(xin - E2) : 0.f;
  float xp = (l < 255) ? *(xin + E2) : 0.f;
  float v = cw[e * 3 + 0] * xm + cw[e * 3 + 1] * x0 + cw[e * 3 + 2] * xp + cb[e];
  xc[idx] = v / (1.f + expf(-v));
}

// ---------------------------------------------------------------------------
// K4: x_proj (33 dots of len 384) + dt_proj + softplus. One wave per (b,l) row.
// ---------------------------------------------------------------------------
__global__ __launch_bounds__(256) void k_xproj(
    const float* __restrict__ xc, const float* __restrict__ xw,
    const float* __restrict__ dtw, const float* __restrict__ dtb,
    float* __restrict__ BC, float* __restrict__ delta)
{
  int wid = threadIdx.x >> 6, lane = threadIdx.x & 63;
  int row = blockIdx.x * 4 + wid;
  const float* xr = xc + (size_t)row * DI;
  float xv[6];
#pragma unroll
  for (int k = 0; k < 6; ++k) xv[k] = xr[lane + 64 * k];
  float dres = 0.f, mine = 0.f;
  for (int j = 0; j < 33; ++j) {
    const float* wr = xw + (size_t)j * DI;
    float p = 0.f;
#pragma unroll
    for (int k = 0; k < 6; ++k) p += wr[lane + 64 * k] * xv[k];
#pragma unroll
    for (int off = 32; off; off >>= 1) p += __shfl_xor(p, off, 64);
    if (j == 0) dres = p;
    else if (lane == j - 1) mine = p;
  }
  if (lane < 32) BC[(size_t)row * 32 + lane] = mine;   // [0..15]=B_mat, [16..31]=C_mat
#pragma unroll
  for (int k = 0; k < 6; ++k) {
    int e = lane + 64 * k;
    float dr = dres * dtw[e] + dtb[e];
    delta[(size_t)row * DI + e] = dr > 20.f ? dr : log1pf(expf(dr));
  }
}

// ---------------------------------------------------------------------------
// K5: chunked selective scan. Block = one (b,e); 256 threads = 16 s x 16
// chunks of 16 steps. Phase 1: per-chunk (prod a, partial h) with 16
// independent unrolled loads (MLP). Phase 2: LDS exclusive combine across
// chunks. Phase 3: replay from registers, shfl-reduce over s, store
// y = (sum_s h*C + xc*D) * silu(z).
// ---------------------------------------------------------------------------
__global__ __launch_bounds__(256) void k_scan(
    const float* __restrict__ delta, const float* __restrict__ xc,
    const float* __restrict__ BC, const float* __restrict__ xz,
    const float* __restrict__ A_log, const float* __restrict__ Dp,
    float* __restrict__ yg)
{
  int blk = blockIdx.x;            // b*DI + e
  int b = blk / DI, e = blk % DI;
  int tid = threadIdx.x;
  int s = tid & 15, ch = tid >> 4;
  float Aes = -expf(A_log[e * DSt + s]);
  size_t rbase = (size_t)b * 256 + ch * 16;   // first row of this chunk
  const float* pd = delta + rbase * DI + e;
  const float* px = xc + rbase * DI + e;
  const float* pb = BC + rbase * 32 + s;
  float a_arr[16], b_arr[16], c_arr[16], x_arr[16];
  float aprod = 1.f, hpart = 0.f;
#pragma unroll
  for (int i = 0; i < 16; ++i) {
    float dv  = pd[(size_t)i * DI];
    float xcv = px[(size_t)i * DI];
    float Bm  = pb[(size_t)i * 32];
    float Cm  = pb[(size_t)i * 32 + 16];
    float da = expf(dv * Aes);
    float bv = dv * Bm * xcv;
    a_arr[i] = da; b_arr[i] = bv; c_arr[i] = Cm; x_arr[i] = xcv;
    hpart = da * hpart + bv;
    aprod *= da;
  }
  __shared__ float Al[16][17], Bl[16][17];
  Al[ch][s] = aprod; Bl[ch][s] = hpart;
  __syncthreads();
  float h = 0.f;
  for (int cc = 0; cc < ch; ++cc)
    h = Al[cc][s] * h + Bl[cc][s];
  float Dv = Dp[e];
  const float* pz = xz + rbase * E2 + DI + e;
  float* py = yg + rbase * DI + e;
#pragma unroll
  for (int i = 0; i < 16; ++i) {
    h = a_arr[i] * h + b_arr[i];
    float contrib = h * c_arr[i];
    contrib += __shfl_xor(contrib, 1, 64);
    contrib += __shfl_xor(contrib, 2, 64);
    contrib += __shfl_xor(contrib, 4, 64);
    contrib += __shfl_xor(contrib, 8, 64);
    if (s == 0) {
      float z = pz[(size_t)i * E2];
      float y = (contrib + x_arr[i] * Dv) * (z / (1.f + expf(-z)));
      py[(size_t)i * DI] = y;
    }
  }
}

// ---------------------------------------------------------------------------
// K6: LayerNorm over d_inner=384, f32 out.
// ---------------------------------------------------------------------------
__global__ __launch_bounds__(128) void k_ln_ssm(
    const float* __restrict__ yg, const float* __restrict__ nw, const float* __restrict__ nb,
    float* __restrict__ yn)
{
  int row = blockIdx.x;
  int t = threadIdx.x;
  const float* yr = yg + (size_t)row * DI;
  float v0 = yr[t], v1 = yr[t + 128], v2 = yr[t + 256];
  float s1 = v0 + v1 + v2, s2 = v0 * v0 + v1 * v1 + v2 * v2;
#pragma unroll
  for (int off = 32; off; off >>= 1) {
    s1 += __shfl_xor(s1, off, 64);
    s2 += __shfl_xor(s2, off, 64);
  }
  __shared__ float a1[2], a2[2];
  if ((t & 63) == 0) { a1[t >> 6] = s1; a2[t >> 6] = s2; }
  __syncthreads();
  float t1 = a1[0] + a1[1], t2 = a2[0] + a2[1];
  float mu = t1 / 384.f, var = t2 / 384.f - mu * mu;
  float rstd = rsqrtf(var + 1e-5f);
  float* yo = yn + (size_t)row * DI;
  yo[t]       = (v0 - mu) * rstd * nw[t]       + nb[t];
  yo[t + 128] = (v1 - mu) * rstd * nw[t + 128] + nb[t + 128];
  yo[t + 256] = (v2 - mu) * rstd * nw[t + 256] + nb[t + 256];
}

// ---------------------------------------------------------------------------
// K8: fused 7x7 depthwise conv + bilinear 4x upsample of ssm + gated combine.
// ---------------------------------------------------------------------------
__global__ __launch_bounds__(256) void k_final(
    const float* __restrict__ x, const float* __restrict__ dww, const float* __restrict__ dwb,
    const float* __restrict__ ssm, const float* __restrict__ gate,
    float* __restrict__ out)
{
  int blk = blockIdx.x;
  int ti = blk & 3;
  int c = (blk >> 2) % C_;
  int b = blk / (4 * C_);
  int h0 = ti * 16;
  __shared__ float xpatch[22 * 72];
  __shared__ float wlds[49];
  __shared__ float slds[6 * 16];
  __shared__ float biass;
  int tid = threadIdx.x;
  if (tid < 49) wlds[tid] = dww[(size_t)c * 49 + tid];
  if (tid == 49) biass = dwb[c];
  int ibase = (h0 >> 2) - 1;   // floor(h0*0.25 - 0.375)
  if (tid < 96) {
    int ii = ibase + (tid >> 4);
    ii = ii < 0 ? 0 : (ii > 15 ? 15 : ii);
    int jj = tid & 15;
    slds[tid] = ssm[((size_t)(b * LS) + ii * 16 + jj) * C_ + c];
  }
  const float* xb = x + ((size_t)(b * C_ + c) * Hh) * Ww;
  for (int idx = tid; idx < 22 * 70; idx += 256) {
    int r = idx / 70, col = idx % 70;
    int gh = h0 - 3 + r, gw = col - 3;
    float v = 0.f;
    if (gh >= 0 && gh < 64 && gw >= 0 && gw < 64)
      v = xb[gh * 64 + gw];
    xpatch[r * 72 + col] = v;
  }
  __syncthreads();
  float g = 1.f / (1.f + expf(-gate[0]));
  int qn = tid >> 5;             // 0..7
  int R0 = qn * 2;
  int w0 = (tid & 31) * 2;
  float a00 = 0, a01 = 0, a10 = 0, a11 = 0;
#pragma unroll
  for (int k = 0; k < 8; ++k) {
    const float* prow = &xpatch[(R0 + k) * 72 + w0];
    float v[8];
#pragma unroll
    for (int d = 0; d < 8; ++d) v[d] = prow[d];
    if (k < 7) {
#pragma unroll
      for (int dx = 0; dx < 7; ++dx) {
        float wv = wlds[k * 7 + dx];
        a00 += wv * v[dx]; a01 += wv * v[dx + 1];
      }
    }
    if (k > 0) {
#pragma unroll
      for (int dx = 0; dx < 7; ++dx) {
        float wv = wlds[(k - 1) * 7 + dx];
        a10 += wv * v[dx]; a11 += wv * v[dx + 1];
      }
    }
  }
  float locs[2][2] = {{a00 + biass, a01 + biass}, {a10 + biass, a11 + biass}};
  float* orow = out + ((size_t)(b * C_ + c) * Hh) * Ww;
#pragma unroll
  for (int rr = 0; rr < 2; ++rr) {
    int hgl = h0 + R0 + rr;
    float ci = hgl * 0.25f - 0.375f;
    float fif = floorf(ci);
    int i0 = (int)fif;
    float fi = ci - fif;
    int li = i0 - ibase;
    const float* r0p = &slds[li * 16];
    const float* r1p = &slds[(li + 1) * 16];
    float ov[2];
#pragma unroll
    for (int ccx = 0; ccx < 2; ++ccx) {
      int wgl = w0 + ccx;
      float cj = wgl * 0.25f - 0.375f;
      float fjf = floorf(cj);
      int j0 = (int)fjf;
      float fj = cj - fjf;
      int jc0 = j0 < 0 ? 0 : j0;
      int jc1 = (j0 + 1) > 15 ? 15 : (j0 + 1);
      float sv = (1.f - fi) * ((1.f - fj) * r0p[jc0] + fj * r0p[jc1])
               +         fi * ((1.f - fj) * r1p[jc0] + fj * r1p[jc1]);
      float xv = xpatch[(R0 + rr + 3) * 72 + (wgl + 3)];
      ov[ccx] = xv + g * sv + (1.f - g) * locs[rr][ccx];
    }
    *reinterpret_cast<float2*>(&orow[hgl * 64 + w0]) = make_float2(ov[0], ov[1]);
  }
}

// ---------------------------------------------------------------------------
extern "C" void kernel_launch(void* const* d_in, const int* in_sizes, int n_in,
                              void* d_out, int out_size, void* d_ws, size_t ws_size,
                              hipStream_t stream)
{
  const float* x    = (const float*)d_in[0];
  const float* inw  = (const float*)d_in[1];
  const float* xw   = (const float*)d_in[2];
  const float* dtw  = (const float*)d_in[3];
  const float* dtb  = (const float*)d_in[4];
  const float* cw   = (const float*)d_in[5];
  const float* cb   = (const float*)d_in[6];
  const float* alog = (const float*)d_in[7];
  const float* Dp   = (const float*)d_in[8];
  const float* ow   = (const float*)d_in[9];
  const float* nsw  = (const float*)d_in[10];
  const float* nsb  = (const float*)d_in[11];
  const float* n1w  = (const float*)d_in[12];
  const float* n1b  = (const float*)d_in[13];
  const float* dww  = (const float*)d_in[14];
  const float* dwb  = (const float*)d_in[15];
  const float* gate = (const float*)d_in[16];

  char* ws = (char*)d_ws;
  float* xln   = (float*)ws; ws += (size_t)8192 * 192 * 4;   // 6.3 MB
  float* xz    = (float*)ws; ws += (size_t)8192 * 768 * 4;   // 25.2 MB
  float* xc    = (float*)ws; ws += (size_t)8192 * 384 * 4;   // 12.6 MB
  float* delta = (float*)ws; ws += (size_t)8192 * 384 * 4;   // 12.6 MB
  float* BC    = (float*)ws; ws += (size_t)8192 * 32 * 4;    // 1.05 MB
  float* yg    = (float*)ws; ws += (size_t)8192 * 384 * 4;   // 12.6 MB
  float* yn  = xz;    // alias: xz dead after k_scan
  float* ssm = xln;   // alias: xln dead after gemm1

  k_pool_ln<<<8192, 192, 0, stream>>>(x, n1w, n1b, xln);
  k_gemm_f32<<<dim3(6, 64), 256, 0, stream>>>(xln, inw, xz, 768, 192);
  k_conv_silu<<<12288, 256, 0, stream>>>(xz, cw, cb, xc);
  k_xproj<<<2048, 256, 0, stream>>>(xc, xw, dtw, dtb, BC, delta);
  k_scan<<<B_ * DI, 256, 0, stream>>>(delta, xc, BC, xz, alog, Dp, yg);
  k_ln_ssm<<<8192, 128, 0, stream>>>(yg, nsw, nsb, yn);
  k_gemm_f32<<<dim3(2, 64), 256, 0, stream>>>(yn, ow, ssm, 192, 384);
  k_final<<<24576, 256, 0, stream>>>(x, dww, dwb, ssm, gate, (float*)d_out);
}